// Round 7
// baseline (261.594 us; speedup 1.0000x reference)
//
#include <hip/hip_runtime.h>
#include <math.h>
#include <stdint.h>

#define HW 512
#define IMG (HW*HW)
#define GS 49                       // gt tile stride in floats: 49 mod 32 = 17 -> 2-way (free) LDS conflicts
#define MLOG32f 3.4657359027997265f
#define WFENCE() __asm__ __volatile__("" ::: "memory")

// strict unfused fp32 to match reference per-op rounding (bin/threshold knife-edge)
__device__ __forceinline__ float grayf(float r, float g, float b) {
    float t = __fadd_rn(__fadd_rn(__fmul_rn(0.299f, r), __fmul_rn(0.587f, g)), __fmul_rn(0.114f, b));
    float s = __fmul_rn(0.5f, __fadd_rn(t, 1.0f));
    return fminf(fmaxf(s, 0.0f), 1.0f);
}

__device__ __forceinline__ float softplusf(float x) {
    return fmaxf(x, 0.0f) + log1pf(expf(-fabsf(x)));
}

__device__ __forceinline__ float frcp(float x)  { return __builtin_amdgcn_rcpf(x); }
__device__ __forceinline__ float frsq(float x)  { return __builtin_amdgcn_rsqf(x); }
__device__ __forceinline__ float flog1p(float x){ return __logf(1.0f + x); }

__device__ __forceinline__ uint64_t kmask(int lo, int hi) {
    return (1ull << hi) - (1ull << lo);
}

// ---------------- K1: gray + per-image histogram (ballot-based, no atomic serialization) ----
__global__ __launch_bounds__(256) void k_gray_hist(const float* __restrict__ img,
                                                   float* __restrict__ gray,
                                                   int* __restrict__ hist) {
    __shared__ int lh[32];
    int tid = threadIdx.x;
    int b = blockIdx.y;
    if (tid < 32) lh[tid] = 0;
    __syncthreads();
    const float4* rp = (const float4*)(img + (size_t)b * 3 * IMG);
    const float4* gp = (const float4*)(img + (size_t)b * 3 * IMG + IMG);
    const float4* bp = (const float4*)(img + (size_t)b * 3 * IMG + 2 * IMG);
    float4* op = (float4*)(gray + (size_t)b * IMG);
    int i = blockIdx.x * 256 + tid;            // float4 index; grid.x = IMG/1024
    float4 r = rp[i], g = gp[i], bb = bp[i];
    float4 o;
    o.x = grayf(r.x, g.x, bb.x);
    o.y = grayf(r.y, g.y, bb.y);
    o.z = grayf(r.z, g.z, bb.z);
    o.w = grayf(r.w, g.w, bb.w);
    op[i] = o;
    int idx[4];
    idx[0] = min(max((int)(o.x * 32.0f), 0), 31);
    idx[1] = min(max((int)(o.y * 32.0f), 0), 31);
    idx[2] = min(max((int)(o.z * 32.0f), 0), 31);
    idx[3] = min(max((int)(o.w * 32.0f), 0), 31);
    int lane = tid & 63;
    int bin = lane & 31;
    int cnt = 0;
    #pragma unroll
    for (int e = 0; e < 4; e++) {
        int v = idx[e];
        unsigned long long m0 = __ballot((v & 1)  != 0);
        unsigned long long m1 = __ballot((v & 2)  != 0);
        unsigned long long m2 = __ballot((v & 4)  != 0);
        unsigned long long m3 = __ballot((v & 8)  != 0);
        unsigned long long m4 = __ballot((v & 16) != 0);
        unsigned long long mm = (bin & 1)  ? m0 : ~m0;
        mm &= (bin & 2)  ? m1 : ~m1;
        mm &= (bin & 4)  ? m2 : ~m2;
        mm &= (bin & 8)  ? m3 : ~m3;
        mm &= (bin & 16) ? m4 : ~m4;
        cnt += __popcll(mm);
    }
    if (lane < 32) atomicAdd(&lh[bin], cnt);   // 32 distinct banks: conflict-free
    __syncthreads();
    if (tid < 32) atomicAdd(&hist[b * 32 + tid], lh[tid]);
}

// ---------------- K2: Otsu per image + scalar constants (merged) ----------------
__global__ void k_otsu_sc(const int* __restrict__ hist,
                          const float* __restrict__ cal_a, const float* __restrict__ cal_b,
                          const float* __restrict__ alpha_logits, const float* __restrict__ tau_p,
                          float* __restrict__ thr, float* __restrict__ sc, int B) {
    int tid = threadIdx.x;
    if (tid < B) {
        const int* h = hist + tid * 32;
        float omega[32], mu[32];
        float co = 0.0f, cm = 0.0f;
        for (int k = 0; k < 32; k++) {
            float pk = (float)h[k] * (1.0f / 262144.0f);   // (H*W+1e-6) rounds to 2^18 in f32
            float xs = (float)((double)k / 31.0);
            co += pk;
            cm += pk * xs;
            omega[k] = co; mu[k] = cm;
        }
        float mu_t = mu[31];
        float best = -1e30f; int kb = 0;
        for (int k = 0; k < 32; k++) {
            float t = mu_t * omega[k] - mu[k];
            float sb = (t * t) / (omega[k] * (1.0f - omega[k]) + 1e-8f);
            if (sb > best) { best = sb; kb = k; }   // first-max, matches jnp.argmax
        }
        thr[tid] = (float)kb * 0.03125f;            // edges[k] = k/32 exact
    }
    if (tid == 63) {
        float al[4];
        float m = -1e30f;
        for (int c = 0; c < 4; c++) { al[c] = alpha_logits[c]; m = fmaxf(m, al[c]); }
        float e[4]; float s = 0.0f;
        for (int c = 0; c < 4; c++) { e[c] = expf(al[c] - m); s += e[c]; }
        float bias = 0.0f;
        for (int c = 0; c < 4; c++) {
            float alpha = e[c] / s;
            sc[c] = alpha * softplusf(cal_a[c]);
            bias += alpha * cal_b[c];
        }
        sc[4] = bias;
        float tau = 0.2f + softplusf(tau_p[0]);
        sc[5] = tau;
        sc[6] = -1.0f / tau;
    }
}

// ---------------- K2b: threshold gray -> packed bits ----------------
__global__ __launch_bounds__(256) void k_thresh(const float* __restrict__ gray,
                                                const float* __restrict__ thr,
                                                uint32_t* __restrict__ packed) {
    int b = blockIdx.y;
    int i = blockIdx.x * 256 + threadIdx.x;
    float t = thr[b];
    float v = gray[(size_t)b * IMG + i];
    unsigned long long m = __ballot(v <= t);
    if ((threadIdx.x & 63) == 0)
        *(uint64_t*)&packed[(size_t)b * 8192 + (i >> 5)] = m;
}

// Sobel + gray/gray^2 9-window row sums for one 4-col item, exact fp association.
// Writes sobel pair to rsP1; returns gray pair per-q in hgs/hg2 (written to LDS later).
__device__ __forceinline__ void sobel_item(const float* __restrict__ gt, float2* __restrict__ rsP1,
                                           int i, int x0, int y0,
                                           float* __restrict__ hgs, float* __restrict__ hg2) {
    int ly = i >> 3, c0 = (i & 7) << 2;
    int gyb = y0 + ly - 4;
    bool rowok = (unsigned)gyb < (unsigned)HW;
    int gx0 = x0 + c0 - 4;
    int base = ly * GS + c0 + 3;
    float a0p = gt[base],          a1p = gt[base + GS],          a2p = gt[base + 2 * GS];
    float a0q = gt[base + 1],      a1q = gt[base + GS + 1],      a2q = gt[base + 2 * GS + 1];
    float sa[12], ca[12], v[12];
    #pragma unroll
    for (int j = 0; j < 12; j++) {
        float a0r = gt[base + 2 + j], a1r = gt[base + GS + 2 + j], a2r = gt[base + 2 * GS + 2 + j];
        v[j] = a1q;                                // gray element (old phase-E value)
        float s = 0.0f, c = 0.0f;
        if (rowok && (unsigned)(gx0 + j) < (unsigned)HW) {
            float gxv = (a0p - a0r) + 2.0f * (a1p - a1r) + (a2p - a2r);
            float gyv = (a0p + 2.0f * a0q + a0r) - (a2p + 2.0f * a2q + a2r);
            float r2 = gxv * gxv + gyv * gyv;
            if (r2 > 0.0f) { float ir = frsq(r2); s = gyv * ir; c = gxv * ir; }
            else { s = 0.0f; c = 1.0f; }
        }
        sa[j] = s; ca[j] = c;
        a0p = a0q; a1p = a1q; a2p = a2q;
        a0q = a0r; a1q = a1r; a2q = a2r;
    }
    float ss = sa[0]+sa[1]+sa[2]+sa[3]+sa[4]+sa[5]+sa[6]+sa[7]+sa[8];
    float cs = ca[0]+ca[1]+ca[2]+ca[3]+ca[4]+ca[5]+ca[6]+ca[7]+ca[8];
    float gs = v[0]+v[1]+v[2]+v[3]+v[4]+v[5]+v[6]+v[7]+v[8];
    float g2 = v[0]*v[0]+v[1]*v[1]+v[2]*v[2]+v[3]*v[3]+v[4]*v[4]+v[5]*v[5]+v[6]*v[6]+v[7]*v[7]+v[8]*v[8];
    #pragma unroll
    for (int q = 0; q < 4; q++) {
        float2 t1; t1.x = ss; t1.y = cs;
        rsP1[(c0 + q) * 41 + ly] = t1;
        hgs[q] = gs; hg2[q] = g2;
        if (q < 3) {
            ss += sa[9 + q] - sa[q]; cs += ca[9 + q] - ca[q];
            gs += v[9 + q] - v[q];
            g2 += v[9 + q] * v[9 + q] - v[q] * v[q];
        }
    }
}

// ---------------- K3: fused morphology + concept maps + E + expsum ----------------
// 4-barrier structure, 22016 B LDS -> 7 blocks/CU. rsP2 aliases the dead gt tile
// (gs/g2 carried in registers across B2); popcount tables eliminated — H computes
// An/Ac/db from broadcast ds_read of nrow/cell/bnd words (integer => exact).
__global__ __launch_bounds__(256, 7) void k_maps(const float* __restrict__ gray,
                                              const uint32_t* __restrict__ p0,
                                              float* __restrict__ zmap,
                                              float* __restrict__ nucf,
                                              float* __restrict__ Eout,
                                              const float* __restrict__ sc,
                                              float* __restrict__ expsum) {
    // LDS map (22016 B):
    //   [0,10496)      gt 42x49 f32 gray tile (phases 0,C'); rsP2 32x41 float2 (after B2)
    //   [10496,20992)  morph transients m0[58] m1[58] dilh[50] ehr[50] (phase 0);
    //                  rsP1 32x41 float2 sobel row-sum pairs (from C' on)
    //   [20992,22000)  persistent bits: nrow[50] bnd[36] cell[40]
    //   [22000,22016)  red[4]
    __shared__ __align__(16) char smem[22016];
    float*    gt   = (float*)smem;
    float2*   rsP2 = (float2*)smem;              // aliases gt (dead after C')
    float2*   rsP1 = (float2*)(smem + 10496);
    uint64_t* m0   = (uint64_t*)(smem + 10496);  // phase-0 transients alias rsP1
    uint64_t* m1   = m0 + 58;
    uint64_t* dilh = m1 + 58;
    uint64_t* ehr  = dilh + 50;
    uint64_t* nrow = (uint64_t*)(smem + 20992);  // persistent
    uint64_t* bnd  = nrow + 50;
    uint64_t* cell = bnd + 36;
    float*    red  = (float*)(smem + 22000);

    int tid = threadIdx.x, b = blockIdx.z;
    int x0 = blockIdx.x * 32, y0 = blockIdx.y * 32;
    int w0 = x0 >> 5;
    const float* gb = gray + (size_t)b * IMG;
    const uint32_t* pb = p0 + (size_t)b * 8192;

    // ---- phase 0: waves 1-3 stage gray tile, wave 0 does bit morphology ----
    if (tid >= 64) {
        for (int s = tid - 64; s < 504; s += 192) {   // 42 rows x 12 float4
            int r = s / 12, c4 = s - r * 12;
            int gy = y0 + r - 5;
            int gxf = (x0 >> 2) + c4 - 2;             // float4 index in row
            float4 v = make_float4(0.f, 0.f, 0.f, 0.f);
            if ((unsigned)gy < (unsigned)HW && (unsigned)gxf < 128u)
                v = *(const float4*)(gb + gy * HW + (gxf << 2));
            float* dst = &gt[r * GS + (c4 << 2)];     // scalar writes: GS odd-ish
            dst[0] = v.x; dst[1] = v.y; dst[2] = v.z; dst[3] = v.w;
        }
    } else {
        int ml = tid;
        // word bit k <-> gx = x0 - 13 + k; stage s output valid on k in [s, 64-s)
        uint64_t mcol = ~0ull;
        if (x0 == 0)   mcol &= ~((1ull << 13) - 1);
        if (x0 == 480) mcol = (1ull << 45) - 1;
        if (ml < 58) {
            int gy = y0 - 13 + ml;
            uint64_t v = 0;
            if ((unsigned)gy < (unsigned)HW) {
                const uint32_t* rowp = pb + gy * 16;
                uint64_t wm = (w0 > 0)  ? rowp[w0 - 1] : 0;
                uint64_t wc = rowp[w0];
                uint64_t wp = (w0 < 15) ? rowp[w0 + 1] : 0;
                v = (wm >> 19) | (wc << 13) | (wp << 45);
            }
            m0[ml] = v;
        }
        WFENCE();
        if (ml >= 1 && ml < 57) {          // erode (pad = 1)
            uint64_t e = ~0ull;
            #pragma unroll
            for (int dt = -1; dt <= 1; dt++) {
                int q = ml + dt;
                int gy = y0 - 13 + q;
                uint64_t vv = ((unsigned)gy < (unsigned)HW) ? (m0[q] | ~mcol) : ~0ull;
                e &= vv & (vv << 1) & (vv >> 1);
            }
            m1[ml] = e;
        }
        WFENCE();
        if (ml >= 2 && ml < 56) {          // dilate (pad = 0)
            uint64_t d = 0;
            #pragma unroll
            for (int dt = -1; dt <= 1; dt++) {
                int q = ml + dt;
                int gy = y0 - 13 + q;
                uint64_t vv = ((unsigned)gy < (unsigned)HW) ? (m1[q] & mcol) : 0;
                d |= vv | (vv << 1) | (vv >> 1);
            }
            m0[ml] = d;
        }
        WFENCE();
        if (ml >= 3 && ml < 55) {          // dilate
            uint64_t d = 0;
            #pragma unroll
            for (int dt = -1; dt <= 1; dt++) {
                int q = ml + dt;
                int gy = y0 - 13 + q;
                uint64_t vv = ((unsigned)gy < (unsigned)HW) ? (m0[q] & mcol) : 0;
                d |= vv | (vv << 1) | (vv >> 1);
            }
            m1[ml] = d;
        }
        WFENCE();
        if (ml >= 4 && ml < 54) {          // erode
            uint64_t e = ~0ull;
            #pragma unroll
            for (int dt = -1; dt <= 1; dt++) {
                int q = ml + dt;
                int gy = y0 - 13 + q;
                uint64_t vv = ((unsigned)gy < (unsigned)HW) ? (m1[q] | ~mcol) : ~0ull;
                e &= vv & (vv << 1) & (vv >> 1);
            }
            m0[ml] = e;
        }
        WFENCE();
        if (ml < 50) {                     // nrow bit k' <-> gx = x0 - 9 + k'
            int gy = y0 - 9 + ml;
            uint64_t v = 0;
            if ((unsigned)gy < (unsigned)HW)
                v = ((m0[ml + 4] & mcol) >> 4) & ((1ull << 50) - 1);
            nrow[ml] = v;
        }
        WFENCE();
        uint64_t mwin = kmask(x0 == 0 ? 9 : 0, x0 == 480 ? 41 : 50);
        if (ml < 50) {
            uint64_t v = nrow[ml];
            uint64_t d = v | (v << 1) | (v >> 1);
            d = d | (d << 2) | (d >> 2);
            d = d | (d << 2) | (d >> 2);
            dilh[ml] = d;
        }
        if (ml >= 6 && ml < 44) {
            int y = y0 - 9 + ml;
            uint64_t m = ((unsigned)y < (unsigned)HW) ? mwin : 0;
            uint64_t v = nrow[ml] | ~m;
            ehr[ml] = v & (v << 1) & (v >> 1);
        }
        WFENCE();
        if (ml < 36) {
            int r = ml + 7;
            uint64_t er = ehr[r - 1] & ehr[r] & ehr[r + 1];
            bnd[ml] = nrow[r] & ~er;
        }
        if (ml < 40) {
            int r = ml + 5;
            int y = y0 - 4 + ml;
            uint64_t c = 0;
            #pragma unroll
            for (int d = -5; d <= 5; d++) c |= dilh[r + d];
            uint64_t m = ((unsigned)y < (unsigned)HW) ? mwin : 0;
            cell[ml] = c & m;
        }
    }
    __syncthreads();   // B1

    // ---- C': Sobel + gray/gray^2 9-window row sums in ONE pass over the gt ring ----
    // Sobel pairs -> rsP1 (LDS); gray pairs held in registers across B2 (rsP2 aliases gt).
    float hgs0[4], hg20[4], hgs1[4], hg21[4];
    sobel_item(gt, rsP1, tid, x0, y0, hgs0, hg20);
    if (tid < 64) sobel_item(gt, rsP1, tid + 256, x0, y0, hgs1, hg21);
    __syncthreads();   // B2 (all gt reads complete)

    // ---- rsP2 write mini-phase (into dead gt region) ----
    {
        int ly = tid >> 3, c0 = (tid & 7) << 2;
        #pragma unroll
        for (int q = 0; q < 4; q++) {
            float2 t; t.x = hgs0[q]; t.y = hg20[q];
            rsP2[(c0 + q) * 41 + ly] = t;
        }
    }
    if (tid < 64) {
        int i = tid + 256; int ly = i >> 3, c0 = (i & 7) << 2;
        #pragma unroll
        for (int q = 0; q < 4; q++) {
            float2 t; t.x = hgs1[q]; t.y = hg21[q];
            rsP2[(c0 + q) * 41 + ly] = t;
        }
    }
    __syncthreads();   // B2b

    // ---- H': z1 + z3 column sums, direct popcounts (broadcast reads), epilogue ----
    int p = tid & 31, py0 = (tid >> 5) << 2;
    int gx = x0 + p;
    float cntx = (float)(min(gx + 4, HW - 1) - max(gx - 4, 0) + 1);
    float z1v[4], z3v[4];
    {
        float2 v[12];
        #pragma unroll
        for (int j = 0; j < 12; j++) v[j] = rsP1[p * 41 + py0 + j];
        float ss = v[0].x+v[1].x+v[2].x+v[3].x+v[4].x+v[5].x+v[6].x+v[7].x+v[8].x;
        float cs = v[0].y+v[1].y+v[2].y+v[3].y+v[4].y+v[5].y+v[6].y+v[7].y+v[8].y;
        #pragma unroll
        for (int q = 0; q < 4; q++) {
            int gy = y0 + py0 + q;
            float cnty = (float)(min(gy + 4, HW - 1) - max(gy - 4, 0) + 1);
            float iden = frcp(cnty * cntx + 1e-6f);
            float ms = ss * iden, mc = cs * iden;
            z1v[q] = 1.0f - sqrtf(ms * ms + mc * mc + 1e-6f);
            if (q < 3) { ss += v[9 + q].x - v[q].x; cs += v[9 + q].y - v[q].y; }
        }
    }
    {
        float2 v[12];
        #pragma unroll
        for (int j = 0; j < 12; j++) v[j] = rsP2[p * 41 + py0 + j];
        float gs = v[0].x+v[1].x+v[2].x+v[3].x+v[4].x+v[5].x+v[6].x+v[7].x+v[8].x;
        float g2 = v[0].y+v[1].y+v[2].y+v[3].y+v[4].y+v[5].y+v[6].y+v[7].y+v[8].y;
        #pragma unroll
        for (int q = 0; q < 4; q++) {
            int gy = y0 + py0 + q;
            float cnty = (float)(min(gy + 4, HW - 1) - max(gy - 4, 0) + 1);
            float iden = frcp(cnty * cntx + 1e-6f);
            float g1 = gs * iden, gq = g2 * iden;
            z3v[q] = flog1p(fmaxf(gq - g1 * g1, 0.0f));
            if (q < 3) { gs += v[9 + q].x - v[q].x; g2 += v[9 + q].y - v[q].y; }
        }
    }
    // direct popcount windows — same-word broadcast LDS reads; integer => exact
    int pn[12], pcc[12], pbv[8];
    #pragma unroll
    for (int j = 0; j < 12; j++) {
        pn[j]  = (int)__popcll((nrow[py0 + 5 + j] >> (p + 5)) & 0x1FFull);
        pcc[j] = (int)__popcll((cell[py0 + j]     >> (p + 5)) & 0x1FFull);
    }
    #pragma unroll
    for (int j = 0; j < 8; j++)
        pbv[j] = (int)__popcll((bnd[py0 + j] >> (p + 7)) & 0x1Full);

    float w0f = sc[0], w1f = sc[1], w2f = sc[2], w3f = sc[3], bias = sc[4], ntau = sc[6];
    float* z0p = zmap + ((size_t)b * 4 + 0) * IMG;
    float* z1p = zmap + ((size_t)b * 4 + 1) * IMG;
    float* z2p = zmap + ((size_t)b * 4 + 2) * IMG;
    float* z3p = zmap + ((size_t)b * 4 + 3) * IMG;
    float* Ep  = Eout + (size_t)b * IMG;
    float* np  = nucf + (size_t)b * IMG;
    float acc = 0.0f;
    {
        int An = pn[0]+pn[1]+pn[2]+pn[3]+pn[4]+pn[5]+pn[6]+pn[7]+pn[8];
        int Ac = pcc[0]+pcc[1]+pcc[2]+pcc[3]+pcc[4]+pcc[5]+pcc[6]+pcc[7]+pcc[8];
        int db = pbv[0]+pbv[1]+pbv[2]+pbv[3]+pbv[4];
        int kk = p + 9;
        #pragma unroll
        for (int q = 0; q < 4; q++) {
            int py = py0 + q;
            int r = py + 9;
            uint64_t rowc = nrow[r];
            int cbit = (int)((rowc >> kk) & 1);
            int nb4  = (int)((nrow[r - 1] >> kk) & 1) + (int)((nrow[r + 1] >> kk) & 1)
                     + (int)((rowc >> (kk - 1)) & 1) + (int)((rowc >> (kk + 1)) & 1);
            int lap = nb4 - 4 * cbit; lap = lap < 0 ? -lap : lap;
            int bc  = (int)((bnd[py + 2] >> kk) & 1);
            float rough = (float)(lap * bc) * frcp((float)db + 1e-6f);
            float z2 = (float)An * frcp(fmaxf((float)(Ac - An), 1.0f));
            float z0s = flog1p(fmaxf(rough, 0.0f));
            float z1s = fminf(fmaxf(z1v[q], 0.0f), 1.0f);
            float z2s = flog1p(fmaxf(z2, 0.0f));
            float z3s = fminf(fmaxf(z3v[q], 0.0f), MLOG32f);
            float E = w0f * z0s + w1f * z1s + w2f * z2s + w3f * z3s + bias;
            int gy = y0 + py;
            size_t o = (size_t)gy * HW + x0 + p;
            z0p[o] = rough;
            z1p[o] = z1v[q];
            z2p[o] = z2;
            z3p[o] = z3v[q];
            Ep[o]  = E;
            np[o]  = (float)cbit;
            acc += __expf(E * ntau);
            if (q < 3) {
                An += pn[9 + q] - pn[q];
                Ac += pcc[9 + q] - pcc[q];
                db += pbv[5 + q] - pbv[q];
            }
        }
    }
    for (int off = 32; off > 0; off >>= 1) acc += __shfl_down(acc, off, 64);
    if ((tid & 63) == 0) red[tid >> 6] = acc;
    __syncthreads();   // B_red
    if (tid == 0) atomicAdd(&expsum[b], red[0] + red[1] + red[2] + red[3]);
}

// ---------------- K5: A = exp(-E/tau) / S ----------------
__global__ __launch_bounds__(256) void k_softmaxA(const float* __restrict__ E,
                                                  float* __restrict__ A,
                                                  const float* __restrict__ sc,
                                                  const float* __restrict__ expsum) {
    int b = blockIdx.y;
    int i = blockIdx.x * 256 + threadIdx.x;
    float ntau = sc[6];
    float invS = 1.0f / expsum[b];
    const float4* Ep = (const float4*)(E + (size_t)b * IMG);
    float4* Ap = (float4*)(A + (size_t)b * IMG);
    float4 e = Ep[i];
    float4 o;
    o.x = __expf(e.x * ntau) * invS;
    o.y = __expf(e.y * ntau) * invS;
    o.z = __expf(e.z * ntau) * invS;
    o.w = __expf(e.w * ntau) * invS;
    Ap[i] = o;
}

extern "C" void kernel_launch(void* const* d_in, const int* in_sizes, int n_in,
                              void* d_out, int out_size, void* d_ws, size_t ws_size,
                              hipStream_t stream) {
    const float* img   = (const float*)d_in[0];
    const float* cal_a = (const float*)d_in[1];
    const float* cal_b = (const float*)d_in[2];
    const float* alpha = (const float*)d_in[3];
    const float* tau_p = (const float*)d_in[4];
    int B = in_sizes[0] / (3 * IMG);

    float* out  = (float*)d_out;
    float* A    = out;                          // (B,1,H,W)
    float* zmap = out + (size_t)B * IMG;        // (B,4,H,W)
    float* nuc  = out + (size_t)B * IMG * 5;    // (B,1,H,W)
    float* E    = out + (size_t)B * IMG * 6;    // (B,1,H,W)
    float* gray = A;                            // A region doubles as gray scratch

    // ws layout: hist(B*32 int) | expsum(B) | thr(B) | sc(8) | packed0
    int*      hist    = (int*)d_ws;
    float*    expsum  = (float*)d_ws + B * 32;
    float*    thr     = expsum + B;
    float*    sc      = thr + B;
    uint32_t* packed0 = (uint32_t*)d_ws + 1024;

    hipMemsetAsync(d_ws, 0, (size_t)(B * 32 + B) * 4, stream);   // hist + expsum
    k_gray_hist<<<dim3(IMG / 1024, B), 256, 0, stream>>>(img, gray, hist);
    k_otsu_sc<<<1, 64, 0, stream>>>(hist, cal_a, cal_b, alpha, tau_p, thr, sc, B);
    k_thresh<<<dim3(IMG / 256, B), 256, 0, stream>>>(gray, thr, packed0);
    dim3 tg(HW / 32, HW / 32, B);
    k_maps<<<tg, 256, 0, stream>>>(gray, packed0, zmap, nuc, E, sc, expsum);
    k_softmaxA<<<dim3(IMG / 1024, B), 256, 0, stream>>>(E, A, sc, expsum);
}

// Round 9
// 259.979 us; speedup vs baseline: 1.0062x; 1.0062x over previous
//
#include <hip/hip_runtime.h>
#include <math.h>
#include <stdint.h>

#define HW 512
#define IMG (HW*HW)
#define GS 49                       // gt tile stride in floats: 49 mod 32 = 17 -> 2-way (free) LDS conflicts
#define MLOG32f 3.4657359027997265f
#define WFENCE() __asm__ __volatile__("" ::: "memory")

// strict unfused fp32 to match reference per-op rounding (bin/threshold knife-edge)
__device__ __forceinline__ float grayf(float r, float g, float b) {
    float t = __fadd_rn(__fadd_rn(__fmul_rn(0.299f, r), __fmul_rn(0.587f, g)), __fmul_rn(0.114f, b));
    float s = __fmul_rn(0.5f, __fadd_rn(t, 1.0f));
    return fminf(fmaxf(s, 0.0f), 1.0f);
}

__device__ __forceinline__ float softplusf(float x) {
    return fmaxf(x, 0.0f) + log1pf(expf(-fabsf(x)));
}

__device__ __forceinline__ float frcp(float x)  { return __builtin_amdgcn_rcpf(x); }
__device__ __forceinline__ float frsq(float x)  { return __builtin_amdgcn_rsqf(x); }
__device__ __forceinline__ float flog1p(float x){ return __logf(1.0f + x); }

__device__ __forceinline__ uint64_t kmask(int lo, int hi) {
    return (1ull << hi) - (1ull << lo);
}

// ---------------- K1: gray + per-image histogram (ballot-based, no atomic serialization) ----
__global__ __launch_bounds__(256) void k_gray_hist(const float* __restrict__ img,
                                                   float* __restrict__ gray,
                                                   int* __restrict__ hist) {
    __shared__ int lh[32];
    int tid = threadIdx.x;
    int b = blockIdx.y;
    if (tid < 32) lh[tid] = 0;
    __syncthreads();
    const float4* rp = (const float4*)(img + (size_t)b * 3 * IMG);
    const float4* gp = (const float4*)(img + (size_t)b * 3 * IMG + IMG);
    const float4* bp = (const float4*)(img + (size_t)b * 3 * IMG + 2 * IMG);
    float4* op = (float4*)(gray + (size_t)b * IMG);
    int i = blockIdx.x * 256 + tid;            // float4 index; grid.x = IMG/1024
    float4 r = rp[i], g = gp[i], bb = bp[i];
    float4 o;
    o.x = grayf(r.x, g.x, bb.x);
    o.y = grayf(r.y, g.y, bb.y);
    o.z = grayf(r.z, g.z, bb.z);
    o.w = grayf(r.w, g.w, bb.w);
    op[i] = o;
    int idx[4];
    idx[0] = min(max((int)(o.x * 32.0f), 0), 31);
    idx[1] = min(max((int)(o.y * 32.0f), 0), 31);
    idx[2] = min(max((int)(o.z * 32.0f), 0), 31);
    idx[3] = min(max((int)(o.w * 32.0f), 0), 31);
    int lane = tid & 63;
    int bin = lane & 31;
    int cnt = 0;
    #pragma unroll
    for (int e = 0; e < 4; e++) {
        int v = idx[e];
        unsigned long long m0 = __ballot((v & 1)  != 0);
        unsigned long long m1 = __ballot((v & 2)  != 0);
        unsigned long long m2 = __ballot((v & 4)  != 0);
        unsigned long long m3 = __ballot((v & 8)  != 0);
        unsigned long long m4 = __ballot((v & 16) != 0);
        unsigned long long mm = (bin & 1)  ? m0 : ~m0;
        mm &= (bin & 2)  ? m1 : ~m1;
        mm &= (bin & 4)  ? m2 : ~m2;
        mm &= (bin & 8)  ? m3 : ~m3;
        mm &= (bin & 16) ? m4 : ~m4;
        cnt += __popcll(mm);
    }
    if (lane < 32) atomicAdd(&lh[bin], cnt);   // 32 distinct banks: conflict-free
    __syncthreads();
    if (tid < 32) atomicAdd(&hist[b * 32 + tid], lh[tid]);
}

// ---------------- K2: Otsu per image + scalar constants (merged) ----------------
__global__ void k_otsu_sc(const int* __restrict__ hist,
                          const float* __restrict__ cal_a, const float* __restrict__ cal_b,
                          const float* __restrict__ alpha_logits, const float* __restrict__ tau_p,
                          float* __restrict__ thr, float* __restrict__ sc, int B) {
    int tid = threadIdx.x;
    if (tid < B) {
        const int* h = hist + tid * 32;
        float omega[32], mu[32];
        float co = 0.0f, cm = 0.0f;
        for (int k = 0; k < 32; k++) {
            float pk = (float)h[k] * (1.0f / 262144.0f);   // (H*W+1e-6) rounds to 2^18 in f32
            float xs = (float)((double)k / 31.0);
            co += pk;
            cm += pk * xs;
            omega[k] = co; mu[k] = cm;
        }
        float mu_t = mu[31];
        float best = -1e30f; int kb = 0;
        for (int k = 0; k < 32; k++) {
            float t = mu_t * omega[k] - mu[k];
            float sb = (t * t) / (omega[k] * (1.0f - omega[k]) + 1e-8f);
            if (sb > best) { best = sb; kb = k; }   // first-max, matches jnp.argmax
        }
        thr[tid] = (float)kb * 0.03125f;            // edges[k] = k/32 exact
    }
    if (tid == 63) {
        float al[4];
        float m = -1e30f;
        for (int c = 0; c < 4; c++) { al[c] = alpha_logits[c]; m = fmaxf(m, al[c]); }
        float e[4]; float s = 0.0f;
        for (int c = 0; c < 4; c++) { e[c] = expf(al[c] - m); s += e[c]; }
        float bias = 0.0f;
        for (int c = 0; c < 4; c++) {
            float alpha = e[c] / s;
            sc[c] = alpha * softplusf(cal_a[c]);
            bias += alpha * cal_b[c];
        }
        sc[4] = bias;
        float tau = 0.2f + softplusf(tau_p[0]);
        sc[5] = tau;
        sc[6] = -1.0f / tau;
    }
}

// ---------------- K2b: threshold gray -> packed bits ----------------
__global__ __launch_bounds__(256) void k_thresh(const float* __restrict__ gray,
                                                const float* __restrict__ thr,
                                                uint32_t* __restrict__ packed) {
    int b = blockIdx.y;
    int i = blockIdx.x * 256 + threadIdx.x;
    float t = thr[b];
    float v = gray[(size_t)b * IMG + i];
    unsigned long long m = __ballot(v <= t);
    if ((threadIdx.x & 63) == 0)
        *(uint64_t*)&packed[(size_t)b * 8192 + (i >> 5)] = m;
}

// C' item body, INLINE (macro, not function): round-6-proven codegen — all arrays
// statically indexed after full unroll so SROA promotes them to registers.
// (Round 7's function-with-pointer-outparams version spilled to scratch: VGPR 44->36,
//  +120 MB phantom HBM traffic.)
#define SOBEL_ITEM(ii, gsv, g2v) { \
    int ly_ = (ii) >> 3, c0_ = ((ii) & 7) << 2; \
    int gyb_ = y0 + ly_ - 4; \
    bool rowok_ = (unsigned)gyb_ < (unsigned)HW; \
    int gx0_ = x0 + c0_ - 4; \
    int base_ = ly_ * GS + c0_ + 3; \
    float a0p = gt[base_],          a1p = gt[base_ + GS],          a2p = gt[base_ + 2 * GS]; \
    float a0q = gt[base_ + 1],      a1q = gt[base_ + GS + 1],      a2q = gt[base_ + 2 * GS + 1]; \
    float sa[12], ca[12], v[12]; \
    _Pragma("unroll") \
    for (int j = 0; j < 12; j++) { \
        float a0r = gt[base_ + 2 + j], a1r = gt[base_ + GS + 2 + j], a2r = gt[base_ + 2 * GS + 2 + j]; \
        v[j] = a1q; \
        float s = 0.0f, c = 0.0f; \
        if (rowok_ && (unsigned)(gx0_ + j) < (unsigned)HW) { \
            float gxv = (a0p - a0r) + 2.0f * (a1p - a1r) + (a2p - a2r); \
            float gyv = (a0p + 2.0f * a0q + a0r) - (a2p + 2.0f * a2q + a2r); \
            float r2 = gxv * gxv + gyv * gyv; \
            if (r2 > 0.0f) { float ir = frsq(r2); s = gyv * ir; c = gxv * ir; } \
            else { s = 0.0f; c = 1.0f; } \
        } \
        sa[j] = s; ca[j] = c; \
        a0p = a0q; a1p = a1q; a2p = a2q; \
        a0q = a0r; a1q = a1r; a2q = a2r; \
    } \
    float ss = sa[0]+sa[1]+sa[2]+sa[3]+sa[4]+sa[5]+sa[6]+sa[7]+sa[8]; \
    float cs = ca[0]+ca[1]+ca[2]+ca[3]+ca[4]+ca[5]+ca[6]+ca[7]+ca[8]; \
    float gs = v[0]+v[1]+v[2]+v[3]+v[4]+v[5]+v[6]+v[7]+v[8]; \
    float g2 = v[0]*v[0]+v[1]*v[1]+v[2]*v[2]+v[3]*v[3]+v[4]*v[4]+v[5]*v[5]+v[6]*v[6]+v[7]*v[7]+v[8]*v[8]; \
    _Pragma("unroll") \
    for (int q = 0; q < 4; q++) { \
        float2 t1; t1.x = ss; t1.y = cs; \
        rsP1[(c0_ + q) * 41 + ly_] = t1; \
        gsv[q] = gs; g2v[q] = g2; \
        if (q < 3) { \
            ss += sa[9 + q] - sa[q]; cs += ca[9 + q] - ca[q]; \
            gs += v[9 + q] - v[q]; \
            g2 += v[9 + q] * v[9 + q] - v[q] * v[q]; \
        } \
    } \
}

// ---------------- K3: fused morphology + concept maps + E + expsum ----------------
// 4-barrier structure, 22016 B LDS -> 7 blocks/CU. rsP2 aliases the dead gt tile
// (gs/g2 carried in registers across B2); popcount tables eliminated — H computes
// An/Ac/db from broadcast ds_read of nrow/cell/bnd words (integer => exact).
__global__ __launch_bounds__(256, 7) void k_maps(const float* __restrict__ gray,
                                              const uint32_t* __restrict__ p0,
                                              float* __restrict__ zmap,
                                              float* __restrict__ nucf,
                                              float* __restrict__ Eout,
                                              const float* __restrict__ sc,
                                              float* __restrict__ expsum) {
    // LDS map (22016 B):
    //   [0,10496)      gt 42x49 f32 gray tile (phases 0,C'); rsP2 32x41 float2 (after B2)
    //   [10496,20992)  morph transients m0[58] m1[58] dilh[50] ehr[50] (phase 0);
    //                  rsP1 32x41 float2 sobel row-sum pairs (from C' on)
    //   [20992,22000)  persistent bits: nrow[50] bnd[36] cell[40]
    //   [22000,22016)  red[4]
    __shared__ __align__(16) char smem[22016];
    float*    gt   = (float*)smem;
    float2*   rsP2 = (float2*)smem;              // aliases gt (dead after C')
    float2*   rsP1 = (float2*)(smem + 10496);
    uint64_t* m0   = (uint64_t*)(smem + 10496);  // phase-0 transients alias rsP1
    uint64_t* m1   = m0 + 58;
    uint64_t* dilh = m1 + 58;
    uint64_t* ehr  = dilh + 50;
    uint64_t* nrow = (uint64_t*)(smem + 20992);  // persistent
    uint64_t* bnd  = nrow + 50;
    uint64_t* cell = bnd + 36;
    float*    red  = (float*)(smem + 22000);

    int tid = threadIdx.x, b = blockIdx.z;
    int x0 = blockIdx.x * 32, y0 = blockIdx.y * 32;
    int w0 = x0 >> 5;
    const float* gb = gray + (size_t)b * IMG;
    const uint32_t* pb = p0 + (size_t)b * 8192;

    // ---- phase 0: waves 1-3 stage gray tile, wave 0 does bit morphology ----
    if (tid >= 64) {
        for (int s = tid - 64; s < 504; s += 192) {   // 42 rows x 12 float4
            int r = s / 12, c4 = s - r * 12;
            int gy = y0 + r - 5;
            int gxf = (x0 >> 2) + c4 - 2;             // float4 index in row
            float4 v = make_float4(0.f, 0.f, 0.f, 0.f);
            if ((unsigned)gy < (unsigned)HW && (unsigned)gxf < 128u)
                v = *(const float4*)(gb + gy * HW + (gxf << 2));
            float* dst = &gt[r * GS + (c4 << 2)];     // scalar writes: GS odd-ish
            dst[0] = v.x; dst[1] = v.y; dst[2] = v.z; dst[3] = v.w;
        }
    } else {
        int ml = tid;
        // word bit k <-> gx = x0 - 13 + k; stage s output valid on k in [s, 64-s)
        uint64_t mcol = ~0ull;
        if (x0 == 0)   mcol &= ~((1ull << 13) - 1);
        if (x0 == 480) mcol = (1ull << 45) - 1;
        if (ml < 58) {
            int gy = y0 - 13 + ml;
            uint64_t v = 0;
            if ((unsigned)gy < (unsigned)HW) {
                const uint32_t* rowp = pb + gy * 16;
                uint64_t wm = (w0 > 0)  ? rowp[w0 - 1] : 0;
                uint64_t wc = rowp[w0];
                uint64_t wp = (w0 < 15) ? rowp[w0 + 1] : 0;
                v = (wm >> 19) | (wc << 13) | (wp << 45);
            }
            m0[ml] = v;
        }
        WFENCE();
        if (ml >= 1 && ml < 57) {          // erode (pad = 1)
            uint64_t e = ~0ull;
            #pragma unroll
            for (int dt = -1; dt <= 1; dt++) {
                int q = ml + dt;
                int gy = y0 - 13 + q;
                uint64_t vv = ((unsigned)gy < (unsigned)HW) ? (m0[q] | ~mcol) : ~0ull;
                e &= vv & (vv << 1) & (vv >> 1);
            }
            m1[ml] = e;
        }
        WFENCE();
        if (ml >= 2 && ml < 56) {          // dilate (pad = 0)
            uint64_t d = 0;
            #pragma unroll
            for (int dt = -1; dt <= 1; dt++) {
                int q = ml + dt;
                int gy = y0 - 13 + q;
                uint64_t vv = ((unsigned)gy < (unsigned)HW) ? (m1[q] & mcol) : 0;
                d |= vv | (vv << 1) | (vv >> 1);
            }
            m0[ml] = d;
        }
        WFENCE();
        if (ml >= 3 && ml < 55) {          // dilate
            uint64_t d = 0;
            #pragma unroll
            for (int dt = -1; dt <= 1; dt++) {
                int q = ml + dt;
                int gy = y0 - 13 + q;
                uint64_t vv = ((unsigned)gy < (unsigned)HW) ? (m0[q] & mcol) : 0;
                d |= vv | (vv << 1) | (vv >> 1);
            }
            m1[ml] = d;
        }
        WFENCE();
        if (ml >= 4 && ml < 54) {          // erode
            uint64_t e = ~0ull;
            #pragma unroll
            for (int dt = -1; dt <= 1; dt++) {
                int q = ml + dt;
                int gy = y0 - 13 + q;
                uint64_t vv = ((unsigned)gy < (unsigned)HW) ? (m1[q] | ~mcol) : ~0ull;
                e &= vv & (vv << 1) & (vv >> 1);
            }
            m0[ml] = e;
        }
        WFENCE();
        if (ml < 50) {                     // nrow bit k' <-> gx = x0 - 9 + k'
            int gy = y0 - 9 + ml;
            uint64_t v = 0;
            if ((unsigned)gy < (unsigned)HW)
                v = ((m0[ml + 4] & mcol) >> 4) & ((1ull << 50) - 1);
            nrow[ml] = v;
        }
        WFENCE();
        uint64_t mwin = kmask(x0 == 0 ? 9 : 0, x0 == 480 ? 41 : 50);
        if (ml < 50) {
            uint64_t v = nrow[ml];
            uint64_t d = v | (v << 1) | (v >> 1);
            d = d | (d << 2) | (d >> 2);
            d = d | (d << 2) | (d >> 2);
            dilh[ml] = d;
        }
        if (ml >= 6 && ml < 44) {
            int y = y0 - 9 + ml;
            uint64_t m = ((unsigned)y < (unsigned)HW) ? mwin : 0;
            uint64_t v = nrow[ml] | ~m;
            ehr[ml] = v & (v << 1) & (v >> 1);
        }
        WFENCE();
        if (ml < 36) {
            int r = ml + 7;
            uint64_t er = ehr[r - 1] & ehr[r] & ehr[r + 1];
            bnd[ml] = nrow[r] & ~er;
        }
        if (ml < 40) {
            int r = ml + 5;
            int y = y0 - 4 + ml;
            uint64_t c = 0;
            #pragma unroll
            for (int d = -5; d <= 5; d++) c |= dilh[r + d];
            uint64_t m = ((unsigned)y < (unsigned)HW) ? mwin : 0;
            cell[ml] = c & m;
        }
    }
    __syncthreads();   // B1

    // ---- C': Sobel + gray/gray^2 9-window row sums in ONE pass over the gt ring ----
    // Sobel pairs -> rsP1 (LDS); gray pairs held in registers across B2 (rsP2 aliases gt).
    float gsA[4], g2A[4], gsB[4], g2B[4];
    SOBEL_ITEM(tid, gsA, g2A)
    if (tid < 64) { SOBEL_ITEM(tid + 256, gsB, g2B) }
    __syncthreads();   // B2 (all gt reads complete)

    // ---- rsP2 write mini-phase (into dead gt region) ----
    {
        int ly = tid >> 3, c0 = (tid & 7) << 2;
        #pragma unroll
        for (int q = 0; q < 4; q++) {
            float2 t; t.x = gsA[q]; t.y = g2A[q];
            rsP2[(c0 + q) * 41 + ly] = t;
        }
    }
    if (tid < 64) {
        int i = tid + 256; int ly = i >> 3, c0 = (i & 7) << 2;
        #pragma unroll
        for (int q = 0; q < 4; q++) {
            float2 t; t.x = gsB[q]; t.y = g2B[q];
            rsP2[(c0 + q) * 41 + ly] = t;
        }
    }
    __syncthreads();   // B2b

    // ---- H': z1 + z3 column sums, direct popcounts (broadcast reads), epilogue ----
    int p = tid & 31, py0 = (tid >> 5) << 2;
    int gx = x0 + p;
    float cntx = (float)(min(gx + 4, HW - 1) - max(gx - 4, 0) + 1);
    float z1v[4], z3v[4];
    {
        float2 v[12];
        #pragma unroll
        for (int j = 0; j < 12; j++) v[j] = rsP1[p * 41 + py0 + j];
        float ss = v[0].x+v[1].x+v[2].x+v[3].x+v[4].x+v[5].x+v[6].x+v[7].x+v[8].x;
        float cs = v[0].y+v[1].y+v[2].y+v[3].y+v[4].y+v[5].y+v[6].y+v[7].y+v[8].y;
        #pragma unroll
        for (int q = 0; q < 4; q++) {
            int gy = y0 + py0 + q;
            float cnty = (float)(min(gy + 4, HW - 1) - max(gy - 4, 0) + 1);
            float iden = frcp(cnty * cntx + 1e-6f);
            float ms = ss * iden, mc = cs * iden;
            z1v[q] = 1.0f - sqrtf(ms * ms + mc * mc + 1e-6f);
            if (q < 3) { ss += v[9 + q].x - v[q].x; cs += v[9 + q].y - v[q].y; }
        }
    }
    {
        float2 v[12];
        #pragma unroll
        for (int j = 0; j < 12; j++) v[j] = rsP2[p * 41 + py0 + j];
        float gs = v[0].x+v[1].x+v[2].x+v[3].x+v[4].x+v[5].x+v[6].x+v[7].x+v[8].x;
        float g2 = v[0].y+v[1].y+v[2].y+v[3].y+v[4].y+v[5].y+v[6].y+v[7].y+v[8].y;
        #pragma unroll
        for (int q = 0; q < 4; q++) {
            int gy = y0 + py0 + q;
            float cnty = (float)(min(gy + 4, HW - 1) - max(gy - 4, 0) + 1);
            float iden = frcp(cnty * cntx + 1e-6f);
            float g1 = gs * iden, gq = g2 * iden;
            z3v[q] = flog1p(fmaxf(gq - g1 * g1, 0.0f));
            if (q < 3) { gs += v[9 + q].x - v[q].x; g2 += v[9 + q].y - v[q].y; }
        }
    }
    // direct popcount windows — same-word broadcast LDS reads; integer => exact
    int pn[12], pcc[12], pbv[8];
    #pragma unroll
    for (int j = 0; j < 12; j++) {
        pn[j]  = (int)__popcll((nrow[py0 + 5 + j] >> (p + 5)) & 0x1FFull);
        pcc[j] = (int)__popcll((cell[py0 + j]     >> (p + 5)) & 0x1FFull);
    }
    #pragma unroll
    for (int j = 0; j < 8; j++)
        pbv[j] = (int)__popcll((bnd[py0 + j] >> (p + 7)) & 0x1Full);

    float w0f = sc[0], w1f = sc[1], w2f = sc[2], w3f = sc[3], bias = sc[4], ntau = sc[6];
    float* z0p = zmap + ((size_t)b * 4 + 0) * IMG;
    float* z1p = zmap + ((size_t)b * 4 + 1) * IMG;
    float* z2p = zmap + ((size_t)b * 4 + 2) * IMG;
    float* z3p = zmap + ((size_t)b * 4 + 3) * IMG;
    float* Ep  = Eout + (size_t)b * IMG;
    float* np  = nucf + (size_t)b * IMG;
    float acc = 0.0f;
    {
        int An = pn[0]+pn[1]+pn[2]+pn[3]+pn[4]+pn[5]+pn[6]+pn[7]+pn[8];
        int Ac = pcc[0]+pcc[1]+pcc[2]+pcc[3]+pcc[4]+pcc[5]+pcc[6]+pcc[7]+pcc[8];
        int db = pbv[0]+pbv[1]+pbv[2]+pbv[3]+pbv[4];
        int kk = p + 9;
        #pragma unroll
        for (int q = 0; q < 4; q++) {
            int py = py0 + q;
            int r = py + 9;
            uint64_t rowc = nrow[r];
            int cbit = (int)((rowc >> kk) & 1);
            int nb4  = (int)((nrow[r - 1] >> kk) & 1) + (int)((nrow[r + 1] >> kk) & 1)
                     + (int)((rowc >> (kk - 1)) & 1) + (int)((rowc >> (kk + 1)) & 1);
            int lap = nb4 - 4 * cbit; lap = lap < 0 ? -lap : lap;
            int bc  = (int)((bnd[py + 2] >> kk) & 1);
            float rough = (float)(lap * bc) * frcp((float)db + 1e-6f);
            float z2 = (float)An * frcp(fmaxf((float)(Ac - An), 1.0f));
            float z0s = flog1p(fmaxf(rough, 0.0f));
            float z1s = fminf(fmaxf(z1v[q], 0.0f), 1.0f);
            float z2s = flog1p(fmaxf(z2, 0.0f));
            float z3s = fminf(fmaxf(z3v[q], 0.0f), MLOG32f);
            float E = w0f * z0s + w1f * z1s + w2f * z2s + w3f * z3s + bias;
            int gy = y0 + py;
            size_t o = (size_t)gy * HW + x0 + p;
            z0p[o] = rough;
            z1p[o] = z1v[q];
            z2p[o] = z2;
            z3p[o] = z3v[q];
            Ep[o]  = E;
            np[o]  = (float)cbit;
            acc += __expf(E * ntau);
            if (q < 3) {
                An += pn[9 + q] - pn[q];
                Ac += pcc[9 + q] - pcc[q];
                db += pbv[5 + q] - pbv[q];
            }
        }
    }
    for (int off = 32; off > 0; off >>= 1) acc += __shfl_down(acc, off, 64);
    if ((tid & 63) == 0) red[tid >> 6] = acc;
    __syncthreads();   // B_red
    if (tid == 0) atomicAdd(&expsum[b], red[0] + red[1] + red[2] + red[3]);
}

// ---------------- K5: A = exp(-E/tau) / S ----------------
__global__ __launch_bounds__(256) void k_softmaxA(const float* __restrict__ E,
                                                  float* __restrict__ A,
                                                  const float* __restrict__ sc,
                                                  const float* __restrict__ expsum) {
    int b = blockIdx.y;
    int i = blockIdx.x * 256 + threadIdx.x;
    float ntau = sc[6];
    float invS = 1.0f / expsum[b];
    const float4* Ep = (const float4*)(E + (size_t)b * IMG);
    float4* Ap = (float4*)(A + (size_t)b * IMG);
    float4 e = Ep[i];
    float4 o;
    o.x = __expf(e.x * ntau) * invS;
    o.y = __expf(e.y * ntau) * invS;
    o.z = __expf(e.z * ntau) * invS;
    o.w = __expf(e.w * ntau) * invS;
    Ap[i] = o;
}

extern "C" void kernel_launch(void* const* d_in, const int* in_sizes, int n_in,
                              void* d_out, int out_size, void* d_ws, size_t ws_size,
                              hipStream_t stream) {
    const float* img   = (const float*)d_in[0];
    const float* cal_a = (const float*)d_in[1];
    const float* cal_b = (const float*)d_in[2];
    const float* alpha = (const float*)d_in[3];
    const float* tau_p = (const float*)d_in[4];
    int B = in_sizes[0] / (3 * IMG);

    float* out  = (float*)d_out;
    float* A    = out;                          // (B,1,H,W)
    float* zmap = out + (size_t)B * IMG;        // (B,4,H,W)
    float* nuc  = out + (size_t)B * IMG * 5;    // (B,1,H,W)
    float* E    = out + (size_t)B * IMG * 6;    // (B,1,H,W)
    float* gray = A;                            // A region doubles as gray scratch

    // ws layout: hist(B*32 int) | expsum(B) | thr(B) | sc(8) | packed0
    int*      hist    = (int*)d_ws;
    float*    expsum  = (float*)d_ws + B * 32;
    float*    thr     = expsum + B;
    float*    sc      = thr + B;
    uint32_t* packed0 = (uint32_t*)d_ws + 1024;

    hipMemsetAsync(d_ws, 0, (size_t)(B * 32 + B) * 4, stream);   // hist + expsum
    k_gray_hist<<<dim3(IMG / 1024, B), 256, 0, stream>>>(img, gray, hist);
    k_otsu_sc<<<1, 64, 0, stream>>>(hist, cal_a, cal_b, alpha, tau_p, thr, sc, B);
    k_thresh<<<dim3(IMG / 256, B), 256, 0, stream>>>(gray, thr, packed0);
    dim3 tg(HW / 32, HW / 32, B);
    k_maps<<<tg, 256, 0, stream>>>(gray, packed0, zmap, nuc, E, sc, expsum);
    k_softmaxA<<<dim3(IMG / 1024, B), 256, 0, stream>>>(E, A, sc, expsum);
}

// Round 10
// 239.838 us; speedup vs baseline: 1.0907x; 1.0840x over previous
//
#include <hip/hip_runtime.h>
#include <math.h>
#include <stdint.h>

#define HW 512
#define IMG (HW*HW)
#define GS 49                       // gt tile stride in floats: 49 mod 32 = 17 -> 2-way (free) LDS conflicts
#define MLOG32f 3.4657359027997265f
#define WFENCE() __asm__ __volatile__("" ::: "memory")

// strict unfused fp32 to match reference per-op rounding (bin/threshold knife-edge)
__device__ __forceinline__ float grayf(float r, float g, float b) {
    float t = __fadd_rn(__fadd_rn(__fmul_rn(0.299f, r), __fmul_rn(0.587f, g)), __fmul_rn(0.114f, b));
    float s = __fmul_rn(0.5f, __fadd_rn(t, 1.0f));
    return fminf(fmaxf(s, 0.0f), 1.0f);
}

__device__ __forceinline__ float softplusf(float x) {
    return fmaxf(x, 0.0f) + log1pf(expf(-fabsf(x)));
}

__device__ __forceinline__ float frcp(float x)  { return __builtin_amdgcn_rcpf(x); }
__device__ __forceinline__ float frsq(float x)  { return __builtin_amdgcn_rsqf(x); }
__device__ __forceinline__ float flog1p(float x){ return __logf(1.0f + x); }

__device__ __forceinline__ uint64_t kmask(int lo, int hi) {
    return (1ull << hi) - (1ull << lo);
}

// ---------------- K1: gray + per-image histogram (ballot-based, no atomic serialization) ----
__global__ __launch_bounds__(256) void k_gray_hist(const float* __restrict__ img,
                                                   float* __restrict__ gray,
                                                   int* __restrict__ hist) {
    __shared__ int lh[32];
    int tid = threadIdx.x;
    int b = blockIdx.y;
    if (tid < 32) lh[tid] = 0;
    __syncthreads();
    const float4* rp = (const float4*)(img + (size_t)b * 3 * IMG);
    const float4* gp = (const float4*)(img + (size_t)b * 3 * IMG + IMG);
    const float4* bp = (const float4*)(img + (size_t)b * 3 * IMG + 2 * IMG);
    float4* op = (float4*)(gray + (size_t)b * IMG);
    int i = blockIdx.x * 256 + tid;            // float4 index; grid.x = IMG/1024
    float4 r = rp[i], g = gp[i], bb = bp[i];
    float4 o;
    o.x = grayf(r.x, g.x, bb.x);
    o.y = grayf(r.y, g.y, bb.y);
    o.z = grayf(r.z, g.z, bb.z);
    o.w = grayf(r.w, g.w, bb.w);
    op[i] = o;
    int idx[4];
    idx[0] = min(max((int)(o.x * 32.0f), 0), 31);
    idx[1] = min(max((int)(o.y * 32.0f), 0), 31);
    idx[2] = min(max((int)(o.z * 32.0f), 0), 31);
    idx[3] = min(max((int)(o.w * 32.0f), 0), 31);
    int lane = tid & 63;
    int bin = lane & 31;
    int cnt = 0;
    #pragma unroll
    for (int e = 0; e < 4; e++) {
        int v = idx[e];
        unsigned long long m0 = __ballot((v & 1)  != 0);
        unsigned long long m1 = __ballot((v & 2)  != 0);
        unsigned long long m2 = __ballot((v & 4)  != 0);
        unsigned long long m3 = __ballot((v & 8)  != 0);
        unsigned long long m4 = __ballot((v & 16) != 0);
        unsigned long long mm = (bin & 1)  ? m0 : ~m0;
        mm &= (bin & 2)  ? m1 : ~m1;
        mm &= (bin & 4)  ? m2 : ~m2;
        mm &= (bin & 8)  ? m3 : ~m3;
        mm &= (bin & 16) ? m4 : ~m4;
        cnt += __popcll(mm);
    }
    if (lane < 32) atomicAdd(&lh[bin], cnt);   // 32 distinct banks: conflict-free
    __syncthreads();
    if (tid < 32) atomicAdd(&hist[b * 32 + tid], lh[tid]);
}

// ---------------- K2: Otsu per image + scalar constants (merged) ----------------
__global__ void k_otsu_sc(const int* __restrict__ hist,
                          const float* __restrict__ cal_a, const float* __restrict__ cal_b,
                          const float* __restrict__ alpha_logits, const float* __restrict__ tau_p,
                          float* __restrict__ thr, float* __restrict__ sc, int B) {
    int tid = threadIdx.x;
    if (tid < B) {
        const int* h = hist + tid * 32;
        float omega[32], mu[32];
        float co = 0.0f, cm = 0.0f;
        for (int k = 0; k < 32; k++) {
            float pk = (float)h[k] * (1.0f / 262144.0f);   // (H*W+1e-6) rounds to 2^18 in f32
            float xs = (float)((double)k / 31.0);
            co += pk;
            cm += pk * xs;
            omega[k] = co; mu[k] = cm;
        }
        float mu_t = mu[31];
        float best = -1e30f; int kb = 0;
        for (int k = 0; k < 32; k++) {
            float t = mu_t * omega[k] - mu[k];
            float sb = (t * t) / (omega[k] * (1.0f - omega[k]) + 1e-8f);
            if (sb > best) { best = sb; kb = k; }   // first-max, matches jnp.argmax
        }
        thr[tid] = (float)kb * 0.03125f;            // edges[k] = k/32 exact
    }
    if (tid == 63) {
        float al[4];
        float m = -1e30f;
        for (int c = 0; c < 4; c++) { al[c] = alpha_logits[c]; m = fmaxf(m, al[c]); }
        float e[4]; float s = 0.0f;
        for (int c = 0; c < 4; c++) { e[c] = expf(al[c] - m); s += e[c]; }
        float bias = 0.0f;
        for (int c = 0; c < 4; c++) {
            float alpha = e[c] / s;
            sc[c] = alpha * softplusf(cal_a[c]);
            bias += alpha * cal_b[c];
        }
        sc[4] = bias;
        float tau = 0.2f + softplusf(tau_p[0]);
        sc[5] = tau;
        sc[6] = -1.0f / tau;
    }
}

// ---------------- K2b: threshold gray -> packed bits ----------------
__global__ __launch_bounds__(256) void k_thresh(const float* __restrict__ gray,
                                                const float* __restrict__ thr,
                                                uint32_t* __restrict__ packed) {
    int b = blockIdx.y;
    int i = blockIdx.x * 256 + threadIdx.x;
    float t = thr[b];
    float v = gray[(size_t)b * IMG + i];
    unsigned long long m = __ballot(v <= t);
    if ((threadIdx.x & 63) == 0)
        *(uint64_t*)&packed[(size_t)b * 8192 + (i >> 5)] = m;
}

// ---------------- K3: fused morphology + concept maps + E + expsum ----------------
// 4-barrier structure: phase C computes BOTH Sobel row-sums and gray/gray^2 row-sums
// from the same register ring (phase E eliminated: its gt reads were exactly the a1q
// ring values); z1/z3 column phases + popcount tables share one phase. LDS 30248 B ->
// 5 blocks/CU (__launch_bounds__ 256,5). VGPR 44 <= 64 quantum: no spill.
// NOTE (r7/r9): do NOT carry the gray sums in registers across a barrier to shrink
// LDS to 7 blocks/CU — that structure needs >64 VGPR and mass-spills (waves/CU halve
// at VGPR 64/128/256, so 7 waves/SIMD forces VGPR<=64).
__global__ __launch_bounds__(256, 5) void k_maps(const float* __restrict__ gray,
                                              const uint32_t* __restrict__ p0,
                                              float* __restrict__ zmap,
                                              float* __restrict__ nucf,
                                              float* __restrict__ Eout,
                                              const float* __restrict__ sc,
                                              float* __restrict__ expsum) {
    // LDS map (30248 B):
    //   [0,8232)       gt 42x49 f32 gray tile
    //   [8232,18728)   rsP1 32x41 float2 sobel row-sum pairs [col][row]
    //                  (phase 0 only: m0[58] m1[58] dilh[50] ehr[50] alias here)
    //   [18728,29224)  rsP2 32x41 float2 gray/gray2 row-sum pairs [col][row]
    //   [29224,30232)  persistent bits: nrow[50] bnd[36] cell[40]
    //   [30232,30248)  red[4]
    //   ints rs_nPT[8][44], rs_cPT[8][44], rs_bPT[8][40] alias gt (dead after C)
    __shared__ __align__(16) char smem[30248];
    float*    gt   = (float*)smem;
    float2*   rsP1 = (float2*)(smem + 8232);
    float2*   rsP2 = (float2*)(smem + 18728);
    uint64_t* m0   = (uint64_t*)(smem + 8232);   // phase-0 transients alias rsP1
    uint64_t* m1   = m0 + 58;
    uint64_t* dilh = m1 + 58;
    uint64_t* ehr  = dilh + 50;
    uint64_t* nrow = (uint64_t*)(smem + 29224);  // persistent
    uint64_t* bnd  = nrow + 50;
    uint64_t* cell = bnd + 36;
    int*      rs_nPT = (int*)smem;               // alias gt (dead after phase C)
    int*      rs_cPT = (int*)(smem + 1408);
    int*      rs_bPT = (int*)(smem + 2816);
    float*    red  = (float*)(smem + 30232);

    int tid = threadIdx.x, b = blockIdx.z;
    int x0 = blockIdx.x * 32, y0 = blockIdx.y * 32;
    int w0 = x0 >> 5;
    const float* gb = gray + (size_t)b * IMG;
    const uint32_t* pb = p0 + (size_t)b * 8192;

    // ---- phase 0: waves 1-3 stage gray tile, wave 0 does bit morphology ----
    if (tid >= 64) {
        for (int s = tid - 64; s < 504; s += 192) {   // 42 rows x 12 float4
            int r = s / 12, c4 = s - r * 12;
            int gy = y0 + r - 5;
            int gxf = (x0 >> 2) + c4 - 2;             // float4 index in row
            float4 v = make_float4(0.f, 0.f, 0.f, 0.f);
            if ((unsigned)gy < (unsigned)HW && (unsigned)gxf < 128u)
                v = *(const float4*)(gb + gy * HW + (gxf << 2));
            float* dst = &gt[r * GS + (c4 << 2)];     // scalar writes: GS odd-ish
            dst[0] = v.x; dst[1] = v.y; dst[2] = v.z; dst[3] = v.w;
        }
    } else {
        int ml = tid;
        // word bit k <-> gx = x0 - 13 + k; stage s output valid on k in [s, 64-s)
        uint64_t mcol = ~0ull;
        if (x0 == 0)   mcol &= ~((1ull << 13) - 1);
        if (x0 == 480) mcol = (1ull << 45) - 1;
        if (ml < 58) {
            int gy = y0 - 13 + ml;
            uint64_t v = 0;
            if ((unsigned)gy < (unsigned)HW) {
                const uint32_t* rowp = pb + gy * 16;
                uint64_t wm = (w0 > 0)  ? rowp[w0 - 1] : 0;
                uint64_t wc = rowp[w0];
                uint64_t wp = (w0 < 15) ? rowp[w0 + 1] : 0;
                v = (wm >> 19) | (wc << 13) | (wp << 45);
            }
            m0[ml] = v;
        }
        WFENCE();
        if (ml >= 1 && ml < 57) {          // erode (pad = 1)
            uint64_t e = ~0ull;
            #pragma unroll
            for (int dt = -1; dt <= 1; dt++) {
                int q = ml + dt;
                int gy = y0 - 13 + q;
                uint64_t vv = ((unsigned)gy < (unsigned)HW) ? (m0[q] | ~mcol) : ~0ull;
                e &= vv & (vv << 1) & (vv >> 1);
            }
            m1[ml] = e;
        }
        WFENCE();
        if (ml >= 2 && ml < 56) {          // dilate (pad = 0)
            uint64_t d = 0;
            #pragma unroll
            for (int dt = -1; dt <= 1; dt++) {
                int q = ml + dt;
                int gy = y0 - 13 + q;
                uint64_t vv = ((unsigned)gy < (unsigned)HW) ? (m1[q] & mcol) : 0;
                d |= vv | (vv << 1) | (vv >> 1);
            }
            m0[ml] = d;
        }
        WFENCE();
        if (ml >= 3 && ml < 55) {          // dilate
            uint64_t d = 0;
            #pragma unroll
            for (int dt = -1; dt <= 1; dt++) {
                int q = ml + dt;
                int gy = y0 - 13 + q;
                uint64_t vv = ((unsigned)gy < (unsigned)HW) ? (m0[q] & mcol) : 0;
                d |= vv | (vv << 1) | (vv >> 1);
            }
            m1[ml] = d;
        }
        WFENCE();
        if (ml >= 4 && ml < 54) {          // erode
            uint64_t e = ~0ull;
            #pragma unroll
            for (int dt = -1; dt <= 1; dt++) {
                int q = ml + dt;
                int gy = y0 - 13 + q;
                uint64_t vv = ((unsigned)gy < (unsigned)HW) ? (m1[q] | ~mcol) : ~0ull;
                e &= vv & (vv << 1) & (vv >> 1);
            }
            m0[ml] = e;
        }
        WFENCE();
        if (ml < 50) {                     // nrow bit k' <-> gx = x0 - 9 + k'
            int gy = y0 - 9 + ml;
            uint64_t v = 0;
            if ((unsigned)gy < (unsigned)HW)
                v = ((m0[ml + 4] & mcol) >> 4) & ((1ull << 50) - 1);
            nrow[ml] = v;
        }
        WFENCE();
        uint64_t mwin = kmask(x0 == 0 ? 9 : 0, x0 == 480 ? 41 : 50);
        if (ml < 50) {
            uint64_t v = nrow[ml];
            uint64_t d = v | (v << 1) | (v >> 1);
            d = d | (d << 2) | (d >> 2);
            d = d | (d << 2) | (d >> 2);
            dilh[ml] = d;
        }
        if (ml >= 6 && ml < 44) {
            int y = y0 - 9 + ml;
            uint64_t m = ((unsigned)y < (unsigned)HW) ? mwin : 0;
            uint64_t v = nrow[ml] | ~m;
            ehr[ml] = v & (v << 1) & (v >> 1);
        }
        WFENCE();
        if (ml < 36) {
            int r = ml + 7;
            uint64_t er = ehr[r - 1] & ehr[r] & ehr[r + 1];
            bnd[ml] = nrow[r] & ~er;
        }
        if (ml < 40) {
            int r = ml + 5;
            int y = y0 - 4 + ml;
            uint64_t c = 0;
            #pragma unroll
            for (int d = -5; d <= 5; d++) c |= dilh[r + d];
            uint64_t m = ((unsigned)y < (unsigned)HW) ? mwin : 0;
            cell[ml] = c & m;
        }
    }
    __syncthreads();   // B1

    // ---- C': Sobel + gray/gray^2 9-window row sums in ONE pass over the gt ring ----
    // At iteration j of the column ring, a1q == gt[(ly+1)*GS + c0+4+j] — exactly the
    // value old phase E re-read from LDS. v[j]=a1q gives bit-identical gray sums free.
    for (int i = tid; i < 320; i += 256) {
        int ly = i >> 3, c0 = (i & 7) << 2;
        int gyb = y0 + ly - 4;
        bool rowok = (unsigned)gyb < (unsigned)HW;
        int gx0 = x0 + c0 - 4;
        int base = ly * GS + c0 + 3;
        float a0p = gt[base],          a1p = gt[base + GS],          a2p = gt[base + 2 * GS];
        float a0q = gt[base + 1],      a1q = gt[base + GS + 1],      a2q = gt[base + 2 * GS + 1];
        float sa[12], ca[12], v[12];
        #pragma unroll
        for (int j = 0; j < 12; j++) {
            float a0r = gt[base + 2 + j], a1r = gt[base + GS + 2 + j], a2r = gt[base + 2 * GS + 2 + j];
            v[j] = a1q;                                // gray element for row-sum (phase-E value)
            float s = 0.0f, c = 0.0f;
            if (rowok && (unsigned)(gx0 + j) < (unsigned)HW) {
                float gxv = (a0p - a0r) + 2.0f * (a1p - a1r) + (a2p - a2r);
                float gyv = (a0p + 2.0f * a0q + a0r) - (a2p + 2.0f * a2q + a2r);
                float r2 = gxv * gxv + gyv * gyv;
                if (r2 > 0.0f) { float ir = frsq(r2); s = gyv * ir; c = gxv * ir; }
                else { s = 0.0f; c = 1.0f; }
            }
            sa[j] = s; ca[j] = c;
            a0p = a0q; a1p = a1q; a2p = a2q;
            a0q = a0r; a1q = a1r; a2q = a2r;
        }
        float ss = sa[0]+sa[1]+sa[2]+sa[3]+sa[4]+sa[5]+sa[6]+sa[7]+sa[8];
        float cs = ca[0]+ca[1]+ca[2]+ca[3]+ca[4]+ca[5]+ca[6]+ca[7]+ca[8];
        float gs = v[0]+v[1]+v[2]+v[3]+v[4]+v[5]+v[6]+v[7]+v[8];
        float g2 = v[0]*v[0]+v[1]*v[1]+v[2]*v[2]+v[3]*v[3]+v[4]*v[4]+v[5]*v[5]+v[6]*v[6]+v[7]*v[7]+v[8]*v[8];
        #pragma unroll
        for (int q = 0; q < 4; q++) {
            float2 t1; t1.x = ss; t1.y = cs;
            float2 t2; t2.x = gs; t2.y = g2;
            rsP1[(c0 + q) * 41 + ly] = t1;
            rsP2[(c0 + q) * 41 + ly] = t2;
            if (q < 3) {
                ss += sa[9 + q] - sa[q]; cs += ca[9 + q] - ca[q];
                gs += v[9 + q] - v[q];
                g2 += v[9 + q] * v[9 + q] - v[q] * v[q];
            }
        }
    }
    __syncthreads();   // B2

    // ---- D': z1 + z3 column sums; G popcount tables (gt-alias, gt now dead) ----
    int p = tid & 31, py0 = (tid >> 5) << 2;
    int gx = x0 + p;
    float cntx = (float)(min(gx + 4, HW - 1) - max(gx - 4, 0) + 1);
    float z1v[4], z3v[4];
    {
        float2 v[12];
        #pragma unroll
        for (int j = 0; j < 12; j++) v[j] = rsP1[p * 41 + py0 + j];
        float ss = v[0].x+v[1].x+v[2].x+v[3].x+v[4].x+v[5].x+v[6].x+v[7].x+v[8].x;
        float cs = v[0].y+v[1].y+v[2].y+v[3].y+v[4].y+v[5].y+v[6].y+v[7].y+v[8].y;
        #pragma unroll
        for (int q = 0; q < 4; q++) {
            int gy = y0 + py0 + q;
            float cnty = (float)(min(gy + 4, HW - 1) - max(gy - 4, 0) + 1);
            float iden = frcp(cnty * cntx + 1e-6f);
            float ms = ss * iden, mc = cs * iden;
            z1v[q] = 1.0f - sqrtf(ms * ms + mc * mc + 1e-6f);
            if (q < 3) { ss += v[9 + q].x - v[q].x; cs += v[9 + q].y - v[q].y; }
        }
    }
    {
        float2 v[12];
        #pragma unroll
        for (int j = 0; j < 12; j++) v[j] = rsP2[p * 41 + py0 + j];
        float gs = v[0].x+v[1].x+v[2].x+v[3].x+v[4].x+v[5].x+v[6].x+v[7].x+v[8].x;
        float g2 = v[0].y+v[1].y+v[2].y+v[3].y+v[4].y+v[5].y+v[6].y+v[7].y+v[8].y;
        #pragma unroll
        for (int q = 0; q < 4; q++) {
            int gy = y0 + py0 + q;
            float cnty = (float)(min(gy + 4, HW - 1) - max(gy - 4, 0) + 1);
            float iden = frcp(cnty * cntx + 1e-6f);
            float g1 = gs * iden, gq = g2 * iden;
            z3v[q] = flog1p(fmaxf(gq - g1 * g1, 0.0f));
            if (q < 3) { gs += v[9 + q].x - v[q].x; g2 += v[9 + q].y - v[q].y; }
        }
    }
    for (int i = tid; i < 320; i += 256) {
        int rr = i >> 3, p8 = i & 7, pbase = p8 << 2;
        uint64_t rn = nrow[rr + 5], rc = cell[rr];
        int vn = 0, vc = 0;
        #pragma unroll
        for (int e = 0; e < 4; e++) {
            int pp = pbase + e;
            vn |= __popcll((rn >> (pp + 5)) & 0x1FFull) << (e * 8);
            vc |= __popcll((rc >> (pp + 5)) & 0x1FFull) << (e * 8);
        }
        rs_nPT[p8 * 44 + rr] = vn;
        rs_cPT[p8 * 44 + rr] = vc;
    }
    for (int i = tid; i < 288; i += 256) {
        int rr = i >> 3, p8 = i & 7, pbase = p8 << 2;
        uint64_t rb = bnd[rr];
        int vb = 0;
        #pragma unroll
        for (int e = 0; e < 4; e++) {
            int pp = pbase + e;
            vb |= __popcll((rb >> (pp + 7)) & 0x1Full) << (e * 8);
        }
        rs_bPT[p8 * 40 + rr] = vb;
    }
    __syncthreads();   // B3

    // ---- H: epilogue (broadcast b128 reads of packed tables, sliding int col sums) ----
    float w0f = sc[0], w1f = sc[1], w2f = sc[2], w3f = sc[3], bias = sc[4], ntau = sc[6];
    float* z0p = zmap + ((size_t)b * 4 + 0) * IMG;
    float* z1p = zmap + ((size_t)b * 4 + 1) * IMG;
    float* z2p = zmap + ((size_t)b * 4 + 2) * IMG;
    float* z3p = zmap + ((size_t)b * 4 + 3) * IMG;
    float* Ep  = Eout + (size_t)b * IMG;
    float* np  = nucf + (size_t)b * IMG;
    float acc = 0.0f;
    {
        int p8 = p >> 2, sh = (p & 3) << 3;
        int4 na = *(const int4*)&rs_nPT[p8 * 44 + py0];
        int4 nb = *(const int4*)&rs_nPT[p8 * 44 + py0 + 4];
        int4 nc = *(const int4*)&rs_nPT[p8 * 44 + py0 + 8];
        int4 ka = *(const int4*)&rs_cPT[p8 * 44 + py0];
        int4 kb = *(const int4*)&rs_cPT[p8 * 44 + py0 + 4];
        int4 kc = *(const int4*)&rs_cPT[p8 * 44 + py0 + 8];
        int4 ba = *(const int4*)&rs_bPT[p8 * 40 + py0];
        int4 bbv = *(const int4*)&rs_bPT[p8 * 40 + py0 + 4];
        int en[12], ec[12], eb[8];
        en[0]=na.x; en[1]=na.y; en[2]=na.z; en[3]=na.w;
        en[4]=nb.x; en[5]=nb.y; en[6]=nb.z; en[7]=nb.w;
        en[8]=nc.x; en[9]=nc.y; en[10]=nc.z; en[11]=nc.w;
        ec[0]=ka.x; ec[1]=ka.y; ec[2]=ka.z; ec[3]=ka.w;
        ec[4]=kb.x; ec[5]=kb.y; ec[6]=kb.z; ec[7]=kb.w;
        ec[8]=kc.x; ec[9]=kc.y; ec[10]=kc.z; ec[11]=kc.w;
        eb[0]=ba.x; eb[1]=ba.y; eb[2]=ba.z; eb[3]=ba.w;
        eb[4]=bbv.x; eb[5]=bbv.y; eb[6]=bbv.z; eb[7]=bbv.w;
        #pragma unroll
        for (int j = 0; j < 12; j++) { en[j] = (en[j] >> sh) & 0xFF; ec[j] = (ec[j] >> sh) & 0xFF; }
        #pragma unroll
        for (int j = 0; j < 8; j++) eb[j] = (eb[j] >> sh) & 0xFF;
        int An = en[0]+en[1]+en[2]+en[3]+en[4]+en[5]+en[6]+en[7]+en[8];
        int Ac = ec[0]+ec[1]+ec[2]+ec[3]+ec[4]+ec[5]+ec[6]+ec[7]+ec[8];
        int db = eb[0]+eb[1]+eb[2]+eb[3]+eb[4];
        int kk = p + 9;
        #pragma unroll
        for (int q = 0; q < 4; q++) {
            int py = py0 + q;
            int r = py + 9;
            uint64_t rowc = nrow[r];
            int cbit = (int)((rowc >> kk) & 1);
            int nb4  = (int)((nrow[r - 1] >> kk) & 1) + (int)((nrow[r + 1] >> kk) & 1)
                     + (int)((rowc >> (kk - 1)) & 1) + (int)((rowc >> (kk + 1)) & 1);
            int lap = nb4 - 4 * cbit; lap = lap < 0 ? -lap : lap;
            int bc  = (int)((bnd[py + 2] >> kk) & 1);
            float rough = (float)(lap * bc) * frcp((float)db + 1e-6f);
            float z2 = (float)An * frcp(fmaxf((float)(Ac - An), 1.0f));
            float z0s = flog1p(fmaxf(rough, 0.0f));
            float z1s = fminf(fmaxf(z1v[q], 0.0f), 1.0f);
            float z2s = flog1p(fmaxf(z2, 0.0f));
            float z3s = fminf(fmaxf(z3v[q], 0.0f), MLOG32f);
            float E = w0f * z0s + w1f * z1s + w2f * z2s + w3f * z3s + bias;
            int gy = y0 + py;
            size_t o = (size_t)gy * HW + x0 + p;
            z0p[o] = rough;
            z1p[o] = z1v[q];
            z2p[o] = z2;
            z3p[o] = z3v[q];
            Ep[o]  = E;
            np[o]  = (float)cbit;
            acc += __expf(E * ntau);
            if (q < 3) {
                An += en[9 + q] - en[q];
                Ac += ec[9 + q] - ec[q];
                db += eb[5 + q] - eb[q];
            }
        }
    }
    for (int off = 32; off > 0; off >>= 1) acc += __shfl_down(acc, off, 64);
    if ((tid & 63) == 0) red[tid >> 6] = acc;
    __syncthreads();   // B4
    if (tid == 0) atomicAdd(&expsum[b], red[0] + red[1] + red[2] + red[3]);
}

// ---------------- K5: A = exp(-E/tau) / S ----------------
__global__ __launch_bounds__(256) void k_softmaxA(const float* __restrict__ E,
                                                  float* __restrict__ A,
                                                  const float* __restrict__ sc,
                                                  const float* __restrict__ expsum) {
    int b = blockIdx.y;
    int i = blockIdx.x * 256 + threadIdx.x;
    float ntau = sc[6];
    float invS = 1.0f / expsum[b];
    const float4* Ep = (const float4*)(E + (size_t)b * IMG);
    float4* Ap = (float4*)(A + (size_t)b * IMG);
    float4 e = Ep[i];
    float4 o;
    o.x = __expf(e.x * ntau) * invS;
    o.y = __expf(e.y * ntau) * invS;
    o.z = __expf(e.z * ntau) * invS;
    o.w = __expf(e.w * ntau) * invS;
    Ap[i] = o;
}

extern "C" void kernel_launch(void* const* d_in, const int* in_sizes, int n_in,
                              void* d_out, int out_size, void* d_ws, size_t ws_size,
                              hipStream_t stream) {
    const float* img   = (const float*)d_in[0];
    const float* cal_a = (const float*)d_in[1];
    const float* cal_b = (const float*)d_in[2];
    const float* alpha = (const float*)d_in[3];
    const float* tau_p = (const float*)d_in[4];
    int B = in_sizes[0] / (3 * IMG);

    float* out  = (float*)d_out;
    float* A    = out;                          // (B,1,H,W)
    float* zmap = out + (size_t)B * IMG;        // (B,4,H,W)
    float* nuc  = out + (size_t)B * IMG * 5;    // (B,1,H,W)
    float* E    = out + (size_t)B * IMG * 6;    // (B,1,H,W)
    float* gray = A;                            // A region doubles as gray scratch

    // ws layout: hist(B*32 int) | expsum(B) | thr(B) | sc(8) | packed0
    int*      hist    = (int*)d_ws;
    float*    expsum  = (float*)d_ws + B * 32;
    float*    thr     = expsum + B;
    float*    sc      = thr + B;
    uint32_t* packed0 = (uint32_t*)d_ws + 1024;

    hipMemsetAsync(d_ws, 0, (size_t)(B * 32 + B) * 4, stream);   // hist + expsum
    k_gray_hist<<<dim3(IMG / 1024, B), 256, 0, stream>>>(img, gray, hist);
    k_otsu_sc<<<1, 64, 0, stream>>>(hist, cal_a, cal_b, alpha, tau_p, thr, sc, B);
    k_thresh<<<dim3(IMG / 256, B), 256, 0, stream>>>(gray, thr, packed0);
    dim3 tg(HW / 32, HW / 32, B);
    k_maps<<<tg, 256, 0, stream>>>(gray, packed0, zmap, nuc, E, sc, expsum);
    k_softmaxA<<<dim3(IMG / 1024, B), 256, 0, stream>>>(E, A, sc, expsum);
}